// Round 1
// baseline (22414.696 us; speedup 1.0000x reference)
//
#include <hip/hip_runtime.h>
#include <cstdint>
#include <cstddef>

// Problem constants
#define B   16
#define SEQ 512
#define HD  768
#define G4  3072   // 4*HD
#define NL  25
#define KSPLIT 8
#define KS  96     // HD / KSPLIT

using u16 = unsigned short;

__device__ __forceinline__ float bf2f(u16 u){
  union { float f; uint32_t i; } v; v.i = ((uint32_t)u) << 16; return v.f;
}
__device__ __forceinline__ u16 f2bf(float f){
  union { float f; uint32_t i; } v; v.f = f;
  uint32_t r = v.i + 0x7FFFu + ((v.i >> 16) & 1u);  // RNE
  return (u16)(r >> 16);
}
__device__ __forceinline__ float sigm(float x){ return 1.f/(1.f + __expf(-x)); }
__device__ __forceinline__ float tanhfast(float x){ return 1.f - 2.f/(__expf(2.f*x) + 1.f); }

struct __align__(8) us4 { u16 x, y, z, w; };
__device__ __forceinline__ float4 ld4(const float* p){ return *(const float4*)p; }
__device__ __forceinline__ float4 ld4(const u16* p){
  us4 v = *(const us4*)p;
  return make_float4(bf2f(v.x), bf2f(v.y), bf2f(v.z), bf2f(v.w));
}

// ---------------------------------------------------------------------------
// prep: WT[lid][k][g] = bf16(w_hh_lid[g][k]);  bias[lid][g] = b_ih+b_hh
// ---------------------------------------------------------------------------
struct WPtrs { const float* w[4]; const float* bi[4]; const float* bh[4]; };

__global__ void prep_kernel(WPtrs p, u16* __restrict__ WT, float* __restrict__ bias){
  const int TOT = 4*HD*G4;
  for (int idx = blockIdx.x*blockDim.x + threadIdx.x; idx < TOT; idx += gridDim.x*blockDim.x){
    int lid = idx / (HD*G4);
    int rem = idx % (HD*G4);
    int k   = rem / G4;
    int g   = rem % G4;
    WT[idx] = f2bf(p.w[lid][(size_t)g*HD + k]);
  }
  for (int idx = blockIdx.x*blockDim.x + threadIdx.x; idx < 4*G4; idx += gridDim.x*blockDim.x){
    int lid = idx / G4, g = idx % G4;
    bias[idx] = p.bi[lid][g] + p.bh[lid][g];
  }
}

// ---------------------------------------------------------------------------
// xg GEMM: out[m][n] = bf16( sum_k A[m][k]*W[n][k] + bias[n] )
// M=8192 fixed, N=3072 fixed, K in {768,1536}. 128x128 tile, 8x8/thread.
// ---------------------------------------------------------------------------
template<typename AT>
__global__ __launch_bounds__(256) void gemm_xg(const AT* __restrict__ A, int K,
    const float* __restrict__ W, const float* __restrict__ bias,
    u16* __restrict__ out)
{
  __shared__ float As[8][128];
  __shared__ float Ws[8][128];
  const int tid = threadIdx.x;
  const int bm = blockIdx.y * 128;
  const int bn = blockIdx.x * 128;
  const int tx = tid & 15, ty = tid >> 4;
  const int lr = tid >> 1;            // 0..127
  const int lc = (tid & 1) * 4;       // 0 or 4
  float acc[8][8] = {};
  for (int k0 = 0; k0 < K; k0 += 8){
    {
      float4 av = ld4(A + (size_t)(bm + lr)*K + (k0 + lc));
      As[lc+0][lr]=av.x; As[lc+1][lr]=av.y; As[lc+2][lr]=av.z; As[lc+3][lr]=av.w;
      float4 wv = *(const float4*)(W + (size_t)(bn + lr)*K + (k0 + lc));
      Ws[lc+0][lr]=wv.x; Ws[lc+1][lr]=wv.y; Ws[lc+2][lr]=wv.z; Ws[lc+3][lr]=wv.w;
    }
    __syncthreads();
    #pragma unroll
    for (int kk = 0; kk < 8; kk++){
      float a[8], bb[8];
      *(float4*)&a[0]  = *(const float4*)&As[kk][ty*8];
      *(float4*)&a[4]  = *(const float4*)&As[kk][ty*8+4];
      *(float4*)&bb[0] = *(const float4*)&Ws[kk][tx*4];
      *(float4*)&bb[4] = *(const float4*)&Ws[kk][64 + tx*4];
      #pragma unroll
      for (int i = 0; i < 8; i++)
        #pragma unroll
        for (int j = 0; j < 8; j++)
          acc[i][j] = fmaf(a[i], bb[j], acc[i][j]);
    }
    __syncthreads();
  }
  float bv[8];
  *(float4*)&bv[0] = *(const float4*)&bias[bn + tx*4];
  *(float4*)&bv[4] = *(const float4*)&bias[bn + 64 + tx*4];
  #pragma unroll
  for (int i = 0; i < 8; i++){
    size_t row = bm + ty*8 + i;
    u16 o0[4], o1[4];
    #pragma unroll
    for (int j = 0; j < 4; j++){
      o0[j] = f2bf(acc[i][j]   + bv[j]);
      o1[j] = f2bf(acc[i][4+j] + bv[4+j]);
    }
    uint2 p0; p0.x = (uint32_t)o0[0] | ((uint32_t)o0[1]<<16); p0.y = (uint32_t)o0[2] | ((uint32_t)o0[3]<<16);
    uint2 p1; p1.x = (uint32_t)o1[0] | ((uint32_t)o1[1]<<16); p1.y = (uint32_t)o1[2] | ((uint32_t)o1[3]<<16);
    *(uint2*)(out + row*G4 + bn + tx*4)      = p0;
    *(uint2*)(out + row*G4 + bn + 64 + tx*4) = p1;
  }
}

// ---------------------------------------------------------------------------
// Scan step kernel 1: partial[ks][dir][b][j] = sum_{k in ks-slice} h[dir][k][b] * Whh[j][k]
// grid = 2 dirs * 24 jblocks * KSPLIT = 384 blocks, 256 thr.
// Thread: 1 j, 8 batches (bh selects b 0-7 or 8-15).
// ---------------------------------------------------------------------------
__global__ __launch_bounds__(256) void lstm_matmul(const u16* __restrict__ WT,
    const float* __restrict__ hstate, float* __restrict__ partial)
{
  const int bid = blockIdx.x;
  const int ks  = bid & 7;
  const int jb  = (bid >> 3) % 24;
  const int dir = bid / (8*24);
  __shared__ float hs[KS*B];   // [k_local][b]
  for (int i = threadIdx.x; i < KS*B; i += 256)
    hs[i] = hstate[(size_t)dir*HD*B + ks*KS*B + i];
  __syncthreads();
  const int jl = threadIdx.x & 127;
  const int bh = threadIdx.x >> 7;
  const int j  = jb*128 + jl;
  const u16* wp = WT + ((size_t)(dir*HD + ks*KS))*G4 + j;
  float acc0=0,acc1=0,acc2=0,acc3=0,acc4=0,acc5=0,acc6=0,acc7=0;
  #pragma unroll 4
  for (int k = 0; k < KS; k++){
    float w = bf2f(wp[(size_t)k*G4]);
    float4 h0 = *(const float4*)&hs[k*B + bh*8];
    float4 h1 = *(const float4*)&hs[k*B + bh*8 + 4];
    acc0 = fmaf(w, h0.x, acc0); acc1 = fmaf(w, h0.y, acc1);
    acc2 = fmaf(w, h0.z, acc2); acc3 = fmaf(w, h0.w, acc3);
    acc4 = fmaf(w, h1.x, acc4); acc5 = fmaf(w, h1.y, acc5);
    acc6 = fmaf(w, h1.z, acc6); acc7 = fmaf(w, h1.w, acc7);
  }
  float* pp = partial + (((size_t)ks*2 + dir)*B + bh*8)*G4 + j;
  pp[0*(size_t)G4]=acc0; pp[1*(size_t)G4]=acc1; pp[2*(size_t)G4]=acc2; pp[3*(size_t)G4]=acc3;
  pp[4*(size_t)G4]=acc4; pp[5*(size_t)G4]=acc5; pp[6*(size_t)G4]=acc6; pp[7*(size_t)G4]=acc7;
}

// ---------------------------------------------------------------------------
// Scan step kernel 2: reduce partials + xg -> gates -> update c,h.
// grid = 32 blocks (dir,b). LAYER==0 writes h1; LAYER==1 fuses tanh+classifier.
// ---------------------------------------------------------------------------
template<int LAYER>
__global__ __launch_bounds__(256) void lstm_gate(const u16* __restrict__ xg,
    const float* __restrict__ partial, float* __restrict__ cstate, float* __restrict__ hstate,
    u16* __restrict__ h1, const float* __restrict__ clf_w, float* __restrict__ logits, int step)
{
  const int dir = blockIdx.x >> 4;
  const int b   = blockIdx.x & 15;
  const int t   = dir ? (SEQ-1-step) : step;
  __shared__ float th[HD];
  const u16* xgp = xg + (((size_t)(dir*B + b))*SEQ + t)*G4;
  for (int jh = threadIdx.x; jh < HD; jh += 256){
    float g[4];
    #pragma unroll
    for (int gate = 0; gate < 4; gate++){
      int j = gate*HD + jh;
      float v = bf2f(xgp[j]);
      #pragma unroll
      for (int ks = 0; ks < KSPLIT; ks++)
        v += partial[(((size_t)ks*2 + dir)*B + b)*G4 + j];
      g[gate] = v;
    }
    float* cp = cstate + ((size_t)dir*B + b)*HD + jh;
    float c  = *cp;
    float ct = sigm(g[1])*c + sigm(g[0])*tanhfast(g[2]);
    float h  = sigm(g[3])*tanhfast(ct);
    *cp = ct;
    hstate[((size_t)dir*HD + jh)*B + b] = h;
    if (LAYER == 0)
      h1[((size_t)b*SEQ + t)*(2*HD) + dir*HD + jh] = f2bf(h);
    else
      th[jh] = tanhfast(h);
  }
  if (LAYER == 1){
    __syncthreads();
    const int wv = threadIdx.x >> 6, lane = threadIdx.x & 63;
    for (int l = wv; l < NL; l += 4){
      const float* cw = clf_w + (size_t)l*(2*HD) + dir*HD;
      float a = 0.f;
      #pragma unroll
      for (int k = lane; k < HD; k += 64) a += th[k]*cw[k];
      #pragma unroll
      for (int off = 32; off >= 1; off >>= 1) a += __shfl_down(a, off);
      if (lane == 0) logits[((size_t)b*SEQ + t)*NL + l] += a;
    }
  }
}

__global__ void logits_init(float* __restrict__ logits, const float* __restrict__ clf_b){
  const int tot = B*SEQ*NL;
  for (int i = blockIdx.x*blockDim.x + threadIdx.x; i < tot; i += gridDim.x*blockDim.x)
    logits[i] = clf_b[i % NL];
}

// ---------------------------------------------------------------------------
// CRF numerator + lengths (per b)
// ---------------------------------------------------------------------------
__global__ __launch_bounds__(256) void crf_num(const float* __restrict__ logits,
    const int* __restrict__ targets, const float* __restrict__ trans,
    const float* __restrict__ start, const float* __restrict__ endv,
    float* __restrict__ numlen)
{
  const int b = blockIdx.x;
  const int* tg = targets + (size_t)b*SEQ;
  float s = 0.f; int cnt = 0;
  for (int t = threadIdx.x; t < SEQ; t += 256){
    int cur = tg[t];
    if (cur >= 0){
      cnt++;
      float e = logits[((size_t)b*SEQ + t)*NL + cur];
      s += e;
      if (t > 0) s += trans[tg[t-1]*NL + cur];   // prefix mask: tg[t-1] >= 0
    }
  }
  __shared__ float ss[256]; __shared__ int sc[256];
  ss[threadIdx.x] = s; sc[threadIdx.x] = cnt;
  __syncthreads();
  for (int o = 128; o > 0; o >>= 1){
    if (threadIdx.x < o){ ss[threadIdx.x] += ss[threadIdx.x+o]; sc[threadIdx.x] += sc[threadIdx.x+o]; }
    __syncthreads();
  }
  if (threadIdx.x == 0){
    int len = sc[0];
    numlen[b]      = ss[0] + start[tg[0]] + endv[tg[len-1]];
    numlen[16 + b] = (float)len;
  }
}

// ---------------------------------------------------------------------------
// CRF forward algorithm (denominator), one wave per b, lane j = state j
// ---------------------------------------------------------------------------
__global__ __launch_bounds__(64) void crf_fwd(const float* __restrict__ logits,
    const int* __restrict__ targets, const float* __restrict__ trans,
    const float* __restrict__ start, const float* __restrict__ endv,
    float* __restrict__ denom)
{
  const int b = blockIdx.x, lane = threadIdx.x;
  __shared__ float tr[NL*NL];
  for (int i = lane; i < NL*NL; i += 64) tr[i] = trans[i];
  __syncthreads();
  const bool act = lane < NL;
  const int j = act ? lane : 0;
  float alpha = act ? (start[j] + logits[(size_t)b*SEQ*NL + j]) : -3e38f;
  const int* tg = targets + (size_t)b*SEQ;
  for (int t = 1; t < SEQ; t++){
    if (tg[t] < 0) break;                     // prefix mask -> alpha frozen afterwards
    float e = logits[((size_t)b*SEQ + t)*NL + j];
    float v[NL]; float mx = -3e38f;
    #pragma unroll
    for (int i = 0; i < NL; i++){
      float ai = __shfl(alpha, i);
      v[i] = ai + tr[i*NL + j];
      mx = fmaxf(mx, v[i]);
    }
    float sum = 0.f;
    #pragma unroll
    for (int i = 0; i < NL; i++) sum += __expf(v[i] - mx);
    float nxt = mx + __logf(sum) + e;
    if (act) alpha = nxt;
  }
  float x = act ? alpha + endv[j] : -3e38f;
  float m2 = x;
  #pragma unroll
  for (int off = 32; off >= 1; off >>= 1) m2 = fmaxf(m2, __shfl_xor(m2, off));
  float se = __expf(x - m2);
  #pragma unroll
  for (int off = 32; off >= 1; off >>= 1) se += __shfl_xor(se, off);
  if (lane == 0) denom[b] = m2 + __logf(se);
}

__global__ void crf_final(const float* __restrict__ numlen, const float* __restrict__ denom,
                          float* __restrict__ out)
{
  if (blockIdx.x == 0 && threadIdx.x == 0){
    float sn = 0.f, sl = 0.f;
    for (int b = 0; b < 16; b++){ sn += numlen[b] - denom[b]; sl += numlen[16+b]; }
    out[0] = -sn / sl;
  }
}

// ---------------------------------------------------------------------------
extern "C" void kernel_launch(void* const* d_in, const int* in_sizes, int n_in,
                              void* d_out, int out_size, void* d_ws, size_t ws_size,
                              hipStream_t stream)
{
  const float* hidden  = (const float*)d_in[0];
  const int*   targets = (const int*)  d_in[1];
  const float* w_ih[4] = {(const float*)d_in[2], (const float*)d_in[6], (const float*)d_in[10], (const float*)d_in[14]};
  const float* w_hh[4] = {(const float*)d_in[3], (const float*)d_in[7], (const float*)d_in[11], (const float*)d_in[15]};
  const float* b_ih[4] = {(const float*)d_in[4], (const float*)d_in[8], (const float*)d_in[12], (const float*)d_in[16]};
  const float* b_hh[4] = {(const float*)d_in[5], (const float*)d_in[9], (const float*)d_in[13], (const float*)d_in[17]};
  const float* clf_w = (const float*)d_in[18];
  const float* clf_b = (const float*)d_in[19];
  const float* trans = (const float*)d_in[20];
  const float* start = (const float*)d_in[21];
  const float* endv  = (const float*)d_in[22];

  // workspace layout (~149 MB total)
  char* p = (char*)d_ws;
  auto alloc = [&](size_t bytes){ void* r = (void*)p; p += (bytes + 255) & ~(size_t)255; return r; };
  u16*   WT      = (u16*)  alloc((size_t)4*HD*G4*2);            // 18.9 MB, [lid][k][g]
  float* bias    = (float*)alloc((size_t)4*G4*4);               // b_ih + b_hh
  u16*   xg      = (u16*)  alloc((size_t)2*B*SEQ*G4*2);         // 100.7 MB, [dir][b][t][g]
  u16*   h1      = (u16*)  alloc((size_t)B*SEQ*2*HD*2);         // 25.2 MB, [b][t][2H]
  float* states  = (float*)alloc((size_t)(2*HD*B + 2*B*HD)*4);  // hstate [dir][k][b]; cstate [dir][b][k]
  float* hstate  = states;
  float* cstate  = states + 2*HD*B;
  float* partial = (float*)alloc((size_t)KSPLIT*2*B*G4*4);      // 3.1 MB
  float* logits  = (float*)alloc((size_t)B*SEQ*NL*4);           // 0.8 MB
  float* numlen  = (float*)alloc(32*4);
  float* denom   = (float*)alloc(16*4);
  if ((size_t)(p - (char*)d_ws) > ws_size) return;  // visible-fail guard if ws too small

  WPtrs wp;
  for (int i = 0; i < 4; i++){ wp.w[i] = w_hh[i]; wp.bi[i] = b_ih[i]; wp.bh[i] = b_hh[i]; }
  prep_kernel<<<4096, 256, 0, stream>>>(wp, WT, bias);

  const dim3 ggrid(24, 64);
  const size_t xg_dir = (size_t)B*SEQ*G4;
  const size_t st_bytes = (size_t)(2*HD*B + 2*B*HD)*4;

  // ---- layer 0 ----
  gemm_xg<float><<<ggrid, 256, 0, stream>>>(hidden, HD, w_ih[0], bias + 0*G4, xg);
  gemm_xg<float><<<ggrid, 256, 0, stream>>>(hidden, HD, w_ih[1], bias + 1*G4, xg + xg_dir);
  hipMemsetAsync(states, 0, st_bytes, stream);
  for (int s = 0; s < SEQ; s++){
    lstm_matmul<<<384, 256, 0, stream>>>(WT, hstate, partial);
    lstm_gate<0><<<32, 256, 0, stream>>>(xg, partial, cstate, hstate, h1, nullptr, nullptr, s);
  }

  // ---- layer 1 ----
  gemm_xg<u16><<<ggrid, 256, 0, stream>>>(h1, 2*HD, w_ih[2], bias + 2*G4, xg);
  gemm_xg<u16><<<ggrid, 256, 0, stream>>>(h1, 2*HD, w_ih[3], bias + 3*G4, xg + xg_dir);
  logits_init<<<256, 256, 0, stream>>>(logits, clf_b);
  hipMemsetAsync(states, 0, st_bytes, stream);
  for (int s = 0; s < SEQ; s++){
    lstm_matmul<<<384, 256, 0, stream>>>(WT + (size_t)2*HD*G4, hstate, partial);
    lstm_gate<1><<<32, 256, 0, stream>>>(xg, partial, cstate, hstate, nullptr, clf_w, logits, s);
  }

  // ---- CRF ----
  crf_num<<<16, 256, 0, stream>>>(logits, targets, trans, start, endv, numlen);
  crf_fwd<<<16, 64, 0, stream>>>(logits, targets, trans, start, endv, denom);
  crf_final<<<1, 64, 0, stream>>>(numlen, denom, (float*)d_out);
}